// Round 2
// baseline (126.626 us; speedup 1.0000x reference)
//
#include <hip/hip_runtime.h>

// GraphInteractionNetwork: B=8, P=512, D=16, E=64, H=128
// h(s,r) = relu(dist(s,r)*w0 + G[s] + br[r]),  G[s] = ns@We1[17:33], br = be1 + nr@We1[1:17]
// agg[r] = (sum_{s != r} h(s,r)) @ We2 + 511*be2
// out[r] = relu([agg[r], n[r]] @ Wn1 + bn1) @ Wn2 + bn2
// R1: packed-fp32 (v_pk_*) main loop: thread owns component pair (j2, j2+64);
//     G stored pre-interleaved as float2(G[j2], G[j2+64]); dist read as float4 (4 receivers).

#define Bc 8
#define Pc 512
#define Dc 16
#define Ec 64
#define Hc 128
#define RT 4   // receivers per block
#define NB 16  // nodes per precompute block

typedef float v2f __attribute__((ext_vector_type(2)));

__device__ __forceinline__ v2f v2fma(v2f a, v2f b, v2f c) {
#if __has_builtin(__builtin_elementwise_fma)
  return __builtin_elementwise_fma(a, b, c);
#else
  v2f r; r.x = fmaf(a.x, b.x, c.x); r.y = fmaf(a.y, b.y, c.y); return r;
#endif
}
__device__ __forceinline__ v2f v2max0(v2f a) {
  v2f z = {0.f, 0.f};
#if __has_builtin(__builtin_elementwise_max)
  return __builtin_elementwise_max(a, z);
#else
  v2f r; r.x = fmaxf(a.x, 0.f); r.y = fmaxf(a.y, 0.f); return r;
#endif
}

// Gp[node][j2] = float2(G[node][j2], G[node][j2+64]),  j2 in [0,64)
__global__ __launch_bounds__(256) void gin_precompute_G(
    const float* __restrict__ hIn, const float* __restrict__ We1, float2* __restrict__ Gp) {
  __shared__ float sW[Dc][Hc];   // We1 rows 17..32 (the ns block), 8 KB
  __shared__ float sN[NB][Dc];   // 1 KB
  const int tid = threadIdx.x;
  for (int i = tid; i < Dc * Hc; i += 256) sW[i >> 7][i & 127] = We1[17 * Hc + i];
  const int base = blockIdx.x * NB;
  for (int i = tid; i < NB * Dc; i += 256) sN[i >> 4][i & 15] = hIn[base * Dc + i];
  __syncthreads();
  for (int idx = tid; idx < NB * 64; idx += 256) {
    int node = idx >> 6, j2 = idx & 63;
    float a0 = 0.f, a1 = 0.f;
#pragma unroll
    for (int d = 0; d < Dc; ++d) {
      float nv = sN[node][d];
      a0 = fmaf(nv, sW[d][j2], a0);
      a1 = fmaf(nv, sW[d][j2 + 64], a1);
    }
    Gp[(base + node) * 64 + j2] = make_float2(a0, a1);
  }
}

__global__ __launch_bounds__(256) void gin_main(
    const float* __restrict__ hIn, const float* __restrict__ We1, const float* __restrict__ be1,
    const float* __restrict__ We2, const float* __restrict__ be2,
    const float* __restrict__ Wn1, const float* __restrict__ bn1,
    const float* __restrict__ Wn2, const float* __restrict__ bn2,
    const float2* __restrict__ Gp, float* __restrict__ out) {
  const int tid = threadIdx.x;
  const int q   = tid >> 6;        // sender quarter (0..3); one wave per quarter
  const int j2  = tid & 63;        // component pair (j2, j2+64)
  const int blk = blockIdx.x;      // b * 128 + rb
  const int b   = blk >> 7;
  const int rb  = blk & 127;
  const int r0  = rb * RT;

  const float*  nodes = hIn + b * Pc * Dc;
  const float2* Gb    = Gp + (size_t)b * Pc * 64;

  __shared__ float4 s_dist4[Pc];         // dist[s] for 4 receivers, 8 KB
  __shared__ float  s_nr[RT][Dc];        // 256 B
  __shared__ v2f    s_part[4][RT][64];   // quarter partial sums, 8 KB
  __shared__ float  s_hsum[RT][Hc];      // 2 KB
  __shared__ float  s_nin[RT][Ec + Dc];  // 1.25 KB
  __shared__ float  s_h2[RT][Hc];        // 2 KB

  if (tid < RT * Dc) s_nr[tid >> 4][tid & 15] = nodes[r0 * Dc + tid];
  __syncthreads();

  // distances: 2 senders per thread, all 4 receivers each, stored as float4
#pragma unroll
  for (int it = 0; it < 2; ++it) {
    int s = tid + it * 256;
    const float4* ns4 = (const float4*)(nodes + s * Dc);
    float nsv[Dc];
    *(float4*)(nsv + 0)  = ns4[0];
    *(float4*)(nsv + 4)  = ns4[1];
    *(float4*)(nsv + 8)  = ns4[2];
    *(float4*)(nsv + 12) = ns4[3];
    float dk[RT];
#pragma unroll
    for (int k = 0; k < RT; ++k) {
      float acc = 0.f;
#pragma unroll
      for (int d = 0; d < Dc; ++d) {
        float df = nsv[d] - s_nr[k][d];
        acc = fmaf(df, df, acc);
      }
      dk[k] = sqrtf(acc);
    }
    s_dist4[s] = make_float4(dk[0], dk[1], dk[2], dk[3]);
  }

  // per-thread packed constants: w0 and receiver biases br
  v2f w02 = {We1[j2], We1[j2 + 64]};
  v2f br2[RT];
  {
    v2f be = {be1[j2], be1[j2 + 64]};
#pragma unroll
    for (int k = 0; k < RT; ++k) br2[k] = be;
#pragma unroll
    for (int d = 0; d < Dc; ++d) {
      v2f wrow = {We1[(1 + d) * Hc + j2], We1[(1 + d) * Hc + j2 + 64]};
#pragma unroll
      for (int k = 0; k < RT; ++k) {
        v2f nv = {s_nr[k][d], s_nr[k][d]};
        br2[k] = v2fma(nv, wrow, br2[k]);
      }
    }
  }
  __syncthreads();  // s_dist4 ready

  // main sender loop: 128 senders per quarter, packed ops cover 2 components
  v2f acc[RT] = {};
  const float2* gq = Gb + (size_t)(q * 128) * 64 + j2;
  const float4* dq = s_dist4 + q * 128;
#pragma unroll 4
  for (int s = 0; s < 128; ++s) {
    float4 d4 = dq[s];                 // broadcast ds_read_b128
    float2 gg = gq[(size_t)s * 64];    // coalesced dwordx2
    v2f g = {gg.x, gg.y};
    v2f dd, t;
    dd = (v2f){d4.x, d4.x}; t = v2fma(dd, w02, g + br2[0]); acc[0] += v2max0(t);
    dd = (v2f){d4.y, d4.y}; t = v2fma(dd, w02, g + br2[1]); acc[1] += v2max0(t);
    dd = (v2f){d4.z, d4.z}; t = v2fma(dd, w02, g + br2[2]); acc[2] += v2max0(t);
    dd = (v2f){d4.w, d4.w}; t = v2fma(dd, w02, g + br2[3]); acc[3] += v2max0(t);
  }
#pragma unroll
  for (int k = 0; k < RT; ++k) s_part[q][k][j2] = acc[k];
  __syncthreads();

  // reduce quarters + remove self-edge (dist=0 there, cancellation is exact)
  {
    int k = q;
    v2f sum = s_part[0][k][j2] + s_part[1][k][j2] + s_part[2][k][j2] + s_part[3][k][j2];
    float2 gg = Gb[(size_t)(r0 + k) * 64 + j2];
    v2f gs = {gg.x, gg.y};
    sum -= v2max0(gs + br2[k]);
    s_hsum[k][j2]      = sum.x;
    s_hsum[k][j2 + 64] = sum.y;
  }
  __syncthreads();

  // agg[k][e] = s_hsum[k] @ We2[:, e] + 511*be2[e]
  {
    int k = tid >> 6, e = tid & 63;
    float a = 511.0f * be2[e];
#pragma unroll 16
    for (int jj = 0; jj < Hc; ++jj) a = fmaf(s_hsum[k][jj], We2[jj * Ec + e], a);
    s_nin[k][e] = a;
  }
  if (tid < RT * Dc) s_nin[tid >> 4][Ec + (tid & 15)] = s_nr[tid >> 4][tid & 15];
  __syncthreads();

  // hidden layer
  {
    const int j = tid & 127;
    const int half = tid >> 7;
#pragma unroll
    for (int kk = 0; kk < 2; ++kk) {
      int k = half * 2 + kk;
      float a = bn1[j];
#pragma unroll 16
      for (int i = 0; i < Ec + Dc; ++i) a = fmaf(s_nin[k][i], Wn1[i * Hc + j], a);
      s_h2[k][j] = fmaxf(a, 0.f);
    }
  }
  __syncthreads();

  // output layer
  if (tid < RT * Dc) {
    int k = tid >> 4, d = tid & 15;
    float a = bn2[d];
#pragma unroll 16
    for (int jj = 0; jj < Hc; ++jj) a = fmaf(s_h2[k][jj], Wn2[jj * Dc + d], a);
    out[b * Pc * Dc + (r0 + k) * Dc + d] = a;
  }
}

extern "C" void kernel_launch(void* const* d_in, const int* in_sizes, int n_in,
                              void* d_out, int out_size, void* d_ws, size_t ws_size,
                              hipStream_t stream) {
  const float* h   = (const float*)d_in[0];
  const float* We1 = (const float*)d_in[1];
  const float* be1 = (const float*)d_in[2];
  const float* We2 = (const float*)d_in[3];
  const float* be2 = (const float*)d_in[4];
  const float* Wn1 = (const float*)d_in[5];
  const float* bn1 = (const float*)d_in[6];
  const float* Wn2 = (const float*)d_in[7];
  const float* bn2 = (const float*)d_in[8];
  float* out = (float*)d_out;
  float2* Gp = (float2*)d_ws;  // B*P*64 float2 = 2 MB

  gin_precompute_G<<<(Bc * Pc) / NB, 256, 0, stream>>>(h, We1, Gp);
  gin_main<<<Bc * (Pc / RT), 256, 0, stream>>>(h, We1, be1, We2, be2, Wn1, bn1, Wn2, bn2, Gp, out);
}

// Round 3
// 112.997 us; speedup vs baseline: 1.1206x; 1.1206x over previous
//
#include <hip/hip_runtime.h>

// GraphInteractionNetwork: B=8, P=512, D=16, E=64, H=128
// h(s,r) = relu(dist(s,r)*w0 + G[s] + br[r]),  G[s] = ns@We1[17:33], br = be1 + nr@We1[1:17]
// agg[r] = (sum_{s != r} h(s,r)) @ We2 + 511*be2
// out[r] = relu([agg[r], n[r]] @ Wn1 + bn1) @ Wn2 + bn2
// R2: RT=8 receivers/block (32 packed ops per 8B G-load) + explicit depth-4
//     register prefetch of G (named regs, static indices) to cover L2 latency.

#define Bc 8
#define Pc 512
#define Dc 16
#define Ec 64
#define Hc 128
#define RT 8   // receivers per block
#define NB 16  // nodes per precompute block

typedef float v2f __attribute__((ext_vector_type(2)));

static __device__ __forceinline__ v2f v2fma(v2f a, v2f b, v2f c) {
#if __has_builtin(__builtin_elementwise_fma)
  return __builtin_elementwise_fma(a, b, c);
#else
  v2f r; r.x = fmaf(a.x, b.x, c.x); r.y = fmaf(a.y, b.y, c.y); return r;
#endif
}
static __device__ __forceinline__ v2f v2max0(v2f a) {
  v2f z = {0.f, 0.f};
#if __has_builtin(__builtin_elementwise_max)
  return __builtin_elementwise_max(a, z);
#else
  v2f r; r.x = fmaxf(a.x, 0.f); r.y = fmaxf(a.y, 0.f); return r;
#endif
}

// Gp[node][j2] = float2(G[node][j2], G[node][j2+64]),  j2 in [0,64)
__global__ __launch_bounds__(256) void gin_precompute_G(
    const float* __restrict__ hIn, const float* __restrict__ We1, float2* __restrict__ Gp) {
  __shared__ float sW[Dc][Hc];   // We1 rows 17..32 (ns block), 8 KB
  __shared__ float sN[NB][Dc];   // 1 KB
  const int tid = threadIdx.x;
  for (int i = tid; i < Dc * Hc; i += 256) sW[i >> 7][i & 127] = We1[17 * Hc + i];
  const int base = blockIdx.x * NB;
  for (int i = tid; i < NB * Dc; i += 256) sN[i >> 4][i & 15] = hIn[base * Dc + i];
  __syncthreads();
  for (int idx = tid; idx < NB * 64; idx += 256) {
    int node = idx >> 6, j2 = idx & 63;
    float a0 = 0.f, a1 = 0.f;
#pragma unroll
    for (int d = 0; d < Dc; ++d) {
      float nv = sN[node][d];
      a0 = fmaf(nv, sW[d][j2], a0);
      a1 = fmaf(nv, sW[d][j2 + 64], a1);
    }
    Gp[(base + node) * 64 + j2] = make_float2(a0, a1);
  }
}

__global__ __launch_bounds__(256) void gin_main(
    const float* __restrict__ hIn, const float* __restrict__ We1, const float* __restrict__ be1,
    const float* __restrict__ We2, const float* __restrict__ be2,
    const float* __restrict__ Wn1, const float* __restrict__ bn1,
    const float* __restrict__ Wn2, const float* __restrict__ bn2,
    const float2* __restrict__ Gp, float* __restrict__ out) {
  const int tid = threadIdx.x;
  const int q   = tid >> 6;        // sender quarter (0..3), one wave each
  const int j2  = tid & 63;        // component pair (j2, j2+64)
  const int blk = blockIdx.x;      // b * 64 + rb
  const int b   = blk >> 6;
  const int rb  = blk & 63;
  const int r0  = rb * RT;

  const float*  nodes = hIn + b * Pc * Dc;
  const float2* Gb    = Gp + (size_t)b * Pc * 64;

  __shared__ float4 s_dA[Pc];            // dist recv 0..3, 8 KB
  __shared__ float4 s_dB[Pc];            // dist recv 4..7, 8 KB
  __shared__ float  s_nr[RT][Dc];        // 512 B
  __shared__ v2f    s_br[RT][64];        // 4 KB
  __shared__ v2f    s_part[4][RT][64];   // 16 KB
  __shared__ float  s_hsum[RT][Hc];      // 4 KB
  __shared__ float  s_nin[RT][Ec + Dc];  // 2.5 KB
  __shared__ float  s_h2[RT][Hc];        // 4 KB

  if (tid < RT * Dc) s_nr[tid >> 4][tid & 15] = nodes[r0 * Dc + tid];
  __syncthreads();

  // distances: 2 senders per thread, all 8 receivers
  for (int s = tid; s < Pc; s += 256) {
    const float4* ns4 = (const float4*)(nodes + s * Dc);
    float nsv[Dc];
    *(float4*)(nsv + 0)  = ns4[0];
    *(float4*)(nsv + 4)  = ns4[1];
    *(float4*)(nsv + 8)  = ns4[2];
    *(float4*)(nsv + 12) = ns4[3];
    float dk[RT];
#pragma unroll
    for (int k = 0; k < RT; ++k) {
      float acc = 0.f;
#pragma unroll
      for (int d = 0; d < Dc; ++d) {
        float df = nsv[d] - s_nr[k][d];
        acc = fmaf(df, df, acc);
      }
      dk[k] = sqrtf(acc);
    }
    s_dA[s] = make_float4(dk[0], dk[1], dk[2], dk[3]);
    s_dB[s] = make_float4(dk[4], dk[5], dk[6], dk[7]);
  }

  // packed per-thread constants
  v2f w02 = {We1[j2], We1[j2 + 64]};
  v2f br[RT];
  {
    v2f be = {be1[j2], be1[j2 + 64]};
#pragma unroll
    for (int k = 0; k < RT; ++k) br[k] = be;
#pragma unroll
    for (int d = 0; d < Dc; ++d) {
      v2f w = {We1[(1 + d) * Hc + j2], We1[(1 + d) * Hc + j2 + 64]};
#pragma unroll
      for (int k = 0; k < RT; ++k) {
        v2f nv = {s_nr[k][d], s_nr[k][d]};
        br[k] = v2fma(nv, w, br[k]);
      }
    }
    if (q == 0) {
#pragma unroll
      for (int k = 0; k < RT; ++k) s_br[k][j2] = br[k];  // for runtime-k reduce phase
    }
  }
  __syncthreads();  // dists + s_br ready

  // main sender loop: 128 senders per quarter, depth-4 register prefetch of G
  v2f acc[RT];
#pragma unroll
  for (int k = 0; k < RT; ++k) acc[k] = (v2f){0.f, 0.f};

  const float2* gp = Gb + (size_t)(q * 128) * 64 + j2;
  const int sbase = q * 128;
  v2f g[4];
#pragma unroll
  for (int i = 0; i < 4; ++i) { float2 t = gp[i * 64]; g[i] = (v2f){t.x, t.y}; }

  for (int sg = 0; sg < 32; ++sg) {
    v2f c[4];
#pragma unroll
    for (int i = 0; i < 4; ++i) c[i] = g[i];
    if (sg != 31) {  // wave-uniform
#pragma unroll
      for (int i = 0; i < 4; ++i) {
        float2 t = gp[(sg * 4 + 4 + i) * 64];
        g[i] = (v2f){t.x, t.y};
      }
    }
#pragma unroll
    for (int i = 0; i < 4; ++i) {
      int s = sbase + sg * 4 + i;
      float4 dA = s_dA[s];   // broadcast
      float4 dB = s_dB[s];
      float dd8[8] = {dA.x, dA.y, dA.z, dA.w, dB.x, dB.y, dB.z, dB.w};
#pragma unroll
      for (int k = 0; k < RT; ++k) {
        v2f dd = {dd8[k], dd8[k]};
        acc[k] += v2max0(v2fma(dd, w02, c[i] + br[k]));
      }
    }
  }
#pragma unroll
  for (int k = 0; k < RT; ++k) s_part[q][k][j2] = acc[k];
  __syncthreads();

  // reduce quarters + remove self-edge (dist = 0 there, exact cancellation)
#pragma unroll
  for (int kk = 0; kk < 2; ++kk) {
    const int k = q + kk * 4;
    v2f sum = s_part[0][k][j2] + s_part[1][k][j2] + s_part[2][k][j2] + s_part[3][k][j2];
    float2 gg = Gb[(size_t)(r0 + k) * 64 + j2];
    v2f gs = {gg.x, gg.y};
    sum -= v2max0(gs + s_br[k][j2]);
    s_hsum[k][j2]      = sum.x;
    s_hsum[k][j2 + 64] = sum.y;
  }
  __syncthreads();

  // agg[k][e] = s_hsum[k] @ We2[:, e] + 511*be2[e]
  {
    const int e = tid & 63;
#pragma unroll
    for (int kk = 0; kk < 2; ++kk) {
      const int k = q + kk * 4;
      float a = 511.0f * be2[e];
#pragma unroll 16
      for (int jj = 0; jj < Hc; ++jj) a = fmaf(s_hsum[k][jj], We2[jj * Ec + e], a);
      s_nin[k][e] = a;
    }
  }
  if (tid < RT * Dc) s_nin[tid >> 4][Ec + (tid & 15)] = s_nr[tid >> 4][tid & 15];
  __syncthreads();

  // hidden layer: 4 receivers per thread
  {
    const int j = tid & 127;
    const int hh = tid >> 7;
#pragma unroll
    for (int kk = 0; kk < 4; ++kk) {
      const int k = hh * 4 + kk;
      float a = bn1[j];
#pragma unroll 16
      for (int i = 0; i < Ec + Dc; ++i) a = fmaf(s_nin[k][i], Wn1[i * Hc + j], a);
      s_h2[k][j] = fmaxf(a, 0.f);
    }
  }
  __syncthreads();

  // output layer
  if (tid < RT * Dc) {
    const int k = tid >> 4, d = tid & 15;
    float a = bn2[d];
#pragma unroll 16
    for (int jj = 0; jj < Hc; ++jj) a = fmaf(s_h2[k][jj], Wn2[jj * Dc + d], a);
    out[b * Pc * Dc + (r0 + k) * Dc + d] = a;
  }
}

extern "C" void kernel_launch(void* const* d_in, const int* in_sizes, int n_in,
                              void* d_out, int out_size, void* d_ws, size_t ws_size,
                              hipStream_t stream) {
  const float* h   = (const float*)d_in[0];
  const float* We1 = (const float*)d_in[1];
  const float* be1 = (const float*)d_in[2];
  const float* We2 = (const float*)d_in[3];
  const float* be2 = (const float*)d_in[4];
  const float* Wn1 = (const float*)d_in[5];
  const float* bn1 = (const float*)d_in[6];
  const float* Wn2 = (const float*)d_in[7];
  const float* bn2 = (const float*)d_in[8];
  float* out = (float*)d_out;
  float2* Gp = (float2*)d_ws;  // B*P*64 float2 = 2 MB

  gin_precompute_G<<<(Bc * Pc) / NB, 256, 0, stream>>>(h, We1, Gp);
  gin_main<<<Bc * (Pc / RT), 256, 0, stream>>>(h, We1, be1, We2, be2, Wn1, bn1, Wn2, bn2, Gp, out);
}